// Round 1
// baseline (176.857 us; speedup 1.0000x reference)
//
#include <hip/hip_runtime.h>

// Problem constants (fixed by the reference): x[B=4, L=2048, H=16, D=64] fp32,
// C = H*D = 1024; filters [C,1,k] for k = 3,7,15,31; outputs = 4 planes of
// [B,L,C] fp32 concatenated in d_out.
constexpr int B = 4;
constexpr int L = 2048;
constexpr int C = 1024;
constexpr int TL = 32;              // l-positions per thread
constexpr int KMAX = 31;
constexpr int HIST = KMAX - 1;      // 30 history values

// Causal cross-correlation semantics (jax conv_general_dilated, pad (k-1,0)):
//   y_k[l] = sum_{j=0}^{k-1} w[j] * x[l - (k-1) + j]
// With xs[m] = x[l0 - 30 + m], index for output i, tap j: 31 - k + i + j.

__global__ __launch_bounds__(256)
void dwfir_kernel(const float* __restrict__ x,
                  const float* __restrict__ f3,
                  const float* __restrict__ f7,
                  const float* __restrict__ f15,
                  const float* __restrict__ f31,
                  float* __restrict__ out)
{
    const int tile = blockIdx.x;                  // L / TL tiles
    const int c    = blockIdx.y * 256 + threadIdx.x;
    const int b    = blockIdx.z;
    const int l0   = tile * TL;

    // ---- filter taps into registers (56 floats) ----
    float w3[3], w7[7], w15[15], w31[31];
#pragma unroll
    for (int j = 0; j < 3;  ++j) w3[j]  = f3 [c * 3  + j];
#pragma unroll
    for (int j = 0; j < 7;  ++j) w7[j]  = f7 [c * 7  + j];
#pragma unroll
    for (int j = 0; j < 15; ++j) w15[j] = f15[c * 15 + j];
#pragma unroll
    for (int j = 0; j < 31; ++j) w31[j] = f31[c * 31 + j];

    // ---- x window into registers, fully static indexing ----
    float xs[TL + HIST];
    const float* xb = x + ((size_t)b * L) * C + c;
#pragma unroll
    for (int m = 0; m < TL + HIST; ++m) {
        const int li = l0 - HIST + m;
        xs[m] = (li >= 0) ? xb[(size_t)li * C] : 0.0f;
    }

    const size_t plane   = (size_t)B * L * C;
    const size_t outBase = ((size_t)b * L + l0) * C + c;

#pragma unroll
    for (int i = 0; i < TL; ++i) {
        float y31 = 0.f, y15 = 0.f, y7 = 0.f, y3 = 0.f;
#pragma unroll
        for (int j = 0; j < 31; ++j) y31 = fmaf(w31[j], xs[i + j],      y31);
#pragma unroll
        for (int j = 0; j < 15; ++j) y15 = fmaf(w15[j], xs[16 + i + j], y15);
#pragma unroll
        for (int j = 0; j < 7;  ++j) y7  = fmaf(w7[j],  xs[24 + i + j], y7);
#pragma unroll
        for (int j = 0; j < 3;  ++j) y3  = fmaf(w3[j],  xs[28 + i + j], y3);

        const size_t o = outBase + (size_t)i * C;
        out[o]             = y3;
        out[o +     plane] = y7;
        out[o + 2 * plane] = y15;
        out[o + 3 * plane] = y31;
    }
}

extern "C" void kernel_launch(void* const* d_in, const int* in_sizes, int n_in,
                              void* d_out, int out_size, void* d_ws, size_t ws_size,
                              hipStream_t stream) {
    const float* x   = (const float*)d_in[0];
    const float* f3  = (const float*)d_in[1];
    const float* f7  = (const float*)d_in[2];
    const float* f15 = (const float*)d_in[3];
    const float* f31 = (const float*)d_in[4];
    float* out = (float*)d_out;

    dim3 grid(L / TL, C / 256, B);
    dim3 block(256);
    dwfir_kernel<<<grid, block, 0, stream>>>(x, f3, f7, f15, f31, out);
}

// Round 2
// 173.347 us; speedup vs baseline: 1.0202x; 1.0202x over previous
//
#include <hip/hip_runtime.h>

// x[B=4, L=2048, C=1024] fp32 (c contiguous); filters [C,1,k] k=3,7,15,31;
// out = 4 planes [B,L,C] fp32 concatenated.
// y_k[l] = sum_{j<k} w[j] * x[l-(k-1)+j]  (causal cross-correlation)

constexpr int B    = 4;
constexpr int L    = 2048;
constexpr int C    = 1024;
constexpr int KMAX = 31;
constexpr int HIST = KMAX - 1;     // 30
constexpr int LT   = 128;          // l-positions per block
constexpr int CB   = 64;           // channels per block
constexpr int ROWS = LT + HIST;    // 158 staged rows
constexpr int SUB  = 32;           // l-positions per thread (LT / 4 sub-tiles)

__global__ __launch_bounds__(256)
void dwfir_kernel(const float* __restrict__ x,
                  const float* __restrict__ f3,
                  const float* __restrict__ f7,
                  const float* __restrict__ f15,
                  const float* __restrict__ f31,
                  float* __restrict__ out)
{
    __shared__ float smem[ROWS][CB];

    const int tid   = threadIdx.x;
    const int l0    = blockIdx.x * LT;          // block's first output l
    const int cbase = blockIdx.y * CB;
    const int b     = blockIdx.z;

    const int c = tid & (CB - 1);               // channel within block
    const int s = tid >> 6;                     // sub-tile 0..3
    const int cg = cbase + c;                   // global channel

    // ---- filter taps into registers (issued before staging for overlap) ----
    float w3[3], w7[7], w15[15], w31[31];
#pragma unroll
    for (int j = 0; j < 3;  ++j) w3[j]  = f3 [cg * 3  + j];
#pragma unroll
    for (int j = 0; j < 7;  ++j) w7[j]  = f7 [cg * 7  + j];
#pragma unroll
    for (int j = 0; j < 15; ++j) w15[j] = f15[cg * 15 + j];
#pragma unroll
    for (int j = 0; j < 31; ++j) w31[j] = f31[cg * 31 + j];

    // ---- stage x[(l0-30) .. (l0+LT-1)] x 64 channels into LDS (float4) ----
    // ROWS rows of 64 floats = 16 float4 each.
    const float* xb = x + ((size_t)b * L) * C + cbase;
    for (int p = tid; p < ROWS * 16; p += 256) {
        const int row  = p >> 4;
        const int col4 = (p & 15) * 4;
        const int l    = l0 - HIST + row;
        float4 v = make_float4(0.f, 0.f, 0.f, 0.f);
        if (l >= 0)
            v = *reinterpret_cast<const float4*>(xb + (size_t)l * C + col4);
        *reinterpret_cast<float4*>(&smem[row][col4]) = v;
    }
    __syncthreads();

    // ---- compute: rolling 31-deep register window over LDS rows ----
    const int r0 = s * SUB;                     // first window row for i=0
    float win[KMAX];
#pragma unroll
    for (int m = 0; m < KMAX; ++m) win[m] = smem[r0 + m][c];

    const size_t plane   = (size_t)B * L * C;
    const size_t outBase = ((size_t)b * L + l0 + s * SUB) * C + cg;

#pragma unroll
    for (int i = 0; i < SUB; ++i) {
        float y31 = 0.f, y15 = 0.f, y7 = 0.f, y3 = 0.f;
#pragma unroll
        for (int j = 0; j < 31; ++j) y31 = fmaf(w31[j], win[j],      y31);
#pragma unroll
        for (int j = 0; j < 15; ++j) y15 = fmaf(w15[j], win[16 + j], y15);
#pragma unroll
        for (int j = 0; j < 7;  ++j) y7  = fmaf(w7[j],  win[24 + j], y7);
#pragma unroll
        for (int j = 0; j < 3;  ++j) y3  = fmaf(w3[j],  win[28 + j], y3);

        const size_t o = outBase + (size_t)i * C;
        __builtin_nontemporal_store(y3,  &out[o]);
        __builtin_nontemporal_store(y7,  &out[o + plane]);
        __builtin_nontemporal_store(y15, &out[o + 2 * plane]);
        __builtin_nontemporal_store(y31, &out[o + 3 * plane]);

        if (i < SUB - 1) {
#pragma unroll
            for (int m = 0; m < KMAX - 1; ++m) win[m] = win[m + 1];
            win[KMAX - 1] = smem[r0 + i + KMAX][c];
        }
    }
}

extern "C" void kernel_launch(void* const* d_in, const int* in_sizes, int n_in,
                              void* d_out, int out_size, void* d_ws, size_t ws_size,
                              hipStream_t stream) {
    const float* x   = (const float*)d_in[0];
    const float* f3  = (const float*)d_in[1];
    const float* f7  = (const float*)d_in[2];
    const float* f15 = (const float*)d_in[3];
    const float* f31 = (const float*)d_in[4];
    float* out = (float*)d_out;

    dim3 grid(L / LT, C / CB, B);   // 16 x 16 x 4 = 1024 blocks
    dim3 block(256);
    dwfir_kernel<<<grid, block, 0, stream>>>(x, f3, f7, f15, f31, out);
}

// Round 3
// 169.286 us; speedup vs baseline: 1.0447x; 1.0240x over previous
//
#include <hip/hip_runtime.h>

// x[B=4, L=2048, C=1024] fp32 (c contiguous); filters [C,1,k] k=3,7,15,31;
// out = 4 planes [B,L,C] fp32 concatenated.
// y_k[l] = sum_{j<k} w[j] * x[l-(k-1)+j]  (causal cross-correlation)
//
// Roofline: 33.5 MB read + 134 MB write = 167.6 MB -> ~26.5 us @ 6.3 TB/s.
// Design: block = 64 channels x 256 l-positions; x window (286 rows x 64 ch,
// 73 KB) staged in LDS -> exactly 2 blocks/CU (146 KB of 160 KB), 16 waves/CU.
// Thread = 1 channel x 32 l-positions; 56 filter taps + 31-deep rolling
// window fully register-resident with static indexing (no scratch).
// Fetch amplification 286/256 = 1.12x; NT stores keep L2 for x reuse.

constexpr int B    = 4;
constexpr int L    = 2048;
constexpr int C    = 1024;
constexpr int KMAX = 31;
constexpr int HIST = KMAX - 1;     // 30
constexpr int LT   = 256;          // l-positions per block
constexpr int CB   = 64;           // channels per block
constexpr int ROWS = LT + HIST;    // 286 staged rows
constexpr int SUB  = 32;           // l-positions per thread
constexpr int NTHR = (LT / SUB) * CB;   // 8 sub-tiles x 64 ch = 512 threads

__global__ __launch_bounds__(NTHR, 4)
void dwfir_kernel(const float* __restrict__ x,
                  const float* __restrict__ f3,
                  const float* __restrict__ f7,
                  const float* __restrict__ f15,
                  const float* __restrict__ f31,
                  float* __restrict__ out)
{
    __shared__ float smem[ROWS][CB];

    const int tid   = threadIdx.x;
    const int l0    = blockIdx.x * LT;          // block's first output l
    const int cbase = blockIdx.y * CB;
    const int b     = blockIdx.z;

    const int c  = tid & (CB - 1);              // channel within block
    const int s  = tid >> 6;                    // sub-tile 0..7
    const int cg = cbase + c;                   // global channel

    // ---- filter taps into registers (issued before staging for overlap) ----
    float w3[3], w7[7], w15[15], w31[31];
#pragma unroll
    for (int j = 0; j < 3;  ++j) w3[j]  = f3 [cg * 3  + j];
#pragma unroll
    for (int j = 0; j < 7;  ++j) w7[j]  = f7 [cg * 7  + j];
#pragma unroll
    for (int j = 0; j < 15; ++j) w15[j] = f15[cg * 15 + j];
#pragma unroll
    for (int j = 0; j < 31; ++j) w31[j] = f31[cg * 31 + j];

    // ---- stage x[(l0-30) .. (l0+LT-1)] x 64 channels into LDS (float4) ----
    // ROWS rows of 64 floats = 16 float4 each -> ROWS*16 = 4576 chunks.
    const float* xb = x + ((size_t)b * L) * C + cbase;
    for (int p = tid; p < ROWS * 16; p += NTHR) {
        const int row  = p >> 4;
        const int col4 = (p & 15) * 4;
        const int l    = l0 - HIST + row;
        float4 v = make_float4(0.f, 0.f, 0.f, 0.f);
        if (l >= 0)
            v = *reinterpret_cast<const float4*>(xb + (size_t)l * C + col4);
        *reinterpret_cast<float4*>(&smem[row][col4]) = v;
    }
    __syncthreads();

    // ---- compute: rolling 31-deep register window over LDS rows ----
    const int r0 = s * SUB;                     // first window row for i=0
    float win[KMAX];
#pragma unroll
    for (int m = 0; m < KMAX; ++m) win[m] = smem[r0 + m][c];

    const size_t plane   = (size_t)B * L * C;
    const size_t outBase = ((size_t)b * L + l0 + s * SUB) * C + cg;

#pragma unroll
    for (int i = 0; i < SUB; ++i) {
        float y31 = 0.f, y15 = 0.f, y7 = 0.f, y3 = 0.f;
#pragma unroll
        for (int j = 0; j < 31; ++j) y31 = fmaf(w31[j], win[j],      y31);
#pragma unroll
        for (int j = 0; j < 15; ++j) y15 = fmaf(w15[j], win[16 + j], y15);
#pragma unroll
        for (int j = 0; j < 7;  ++j) y7  = fmaf(w7[j],  win[24 + j], y7);
#pragma unroll
        for (int j = 0; j < 3;  ++j) y3  = fmaf(w3[j],  win[28 + j], y3);

        const size_t o = outBase + (size_t)i * C;
        __builtin_nontemporal_store(y3,  &out[o]);
        __builtin_nontemporal_store(y7,  &out[o + plane]);
        __builtin_nontemporal_store(y15, &out[o + 2 * plane]);
        __builtin_nontemporal_store(y31, &out[o + 3 * plane]);

        if (i < SUB - 1) {
#pragma unroll
            for (int m = 0; m < KMAX - 1; ++m) win[m] = win[m + 1];
            win[KMAX - 1] = smem[r0 + i + KMAX][c];
        }
    }
}

extern "C" void kernel_launch(void* const* d_in, const int* in_sizes, int n_in,
                              void* d_out, int out_size, void* d_ws, size_t ws_size,
                              hipStream_t stream) {
    const float* x   = (const float*)d_in[0];
    const float* f3  = (const float*)d_in[1];
    const float* f7  = (const float*)d_in[2];
    const float* f15 = (const float*)d_in[3];
    const float* f31 = (const float*)d_in[4];
    float* out = (float*)d_out;

    dim3 grid(L / LT, C / CB, B);   // 8 x 16 x 4 = 512 blocks
    dim3 block(NTHR);
    dwfir_kernel<<<grid, block, 0, stream>>>(x, f3, f7, f15, f31, out);
}